// Round 2
// baseline (711.911 us; speedup 1.0000x reference)
//
#include <hip/hip_runtime.h>
#include <hip/hip_bf16.h>
#include <math.h>

#define E_NUM 800000
#define NN 50000
#define NG 50
#define NTW (E_NUM / 16)        // 16-edge wave-tiles
#define EDGE_BLOCKS 768         // 3 blocks/CU

typedef __bf16 bf16x8 __attribute__((ext_vector_type(8)));
typedef float f32x4 __attribute__((ext_vector_type(4)));
typedef unsigned short ushortx8 __attribute__((ext_vector_type(8)));

// native f32->bf16 (RNE)
__device__ __forceinline__ unsigned short f2b(float f) {
  union { __bf16 h; unsigned short u; } v; v.h = (__bf16)f; return v.u;
}
__device__ __forceinline__ float b2f(unsigned short u) {
  union { unsigned u; float f; } v; v.u = ((unsigned)u) << 16; return v.f;
}
// shifted softplus via hw exp2/log2
__device__ __forceinline__ float sspf(float v) {
  float e = __builtin_amdgcn_exp2f(-1.4426950408889634f * fabsf(v));
  return fmaxf(v, 0.f) + 0.6931471805599453f * __builtin_amdgcn_logf(fmaf(0.5f, e, 0.5f));
}

// ---------------- counting sort by dst ----------------
__global__ __launch_bounds__(256) void k_hist(const int* __restrict__ ei, int* __restrict__ counts) {
  int e = blockIdx.x * 256 + threadIdx.x;
  if (e < E_NUM) atomicAdd(&counts[ei[E_NUM + e]], 1);
}

__global__ __launch_bounds__(1024) void k_scan(const int* __restrict__ counts,
                                               int* __restrict__ cursor) {
  __shared__ int tot[1024];
  const int t = threadIdx.x;
  const int C = (NN + 1023) >> 10;  // 49
  int lo = t * C, hi = lo + C; if (hi > NN) hi = NN; if (lo > NN) lo = NN;
  int s = 0;
  for (int i = lo; i < hi; ++i) s += counts[i];
  tot[t] = s;
  __syncthreads();
  int mine = s;
  for (int o = 1; o < 1024; o <<= 1) {
    int v = (t >= o) ? tot[t - o] : 0;
    __syncthreads();
    tot[t] += v;
    __syncthreads();
  }
  int run = tot[t] - mine;
  for (int i = lo; i < hi; ++i) { int c = counts[i]; cursor[i] = run; run += c; }
}

// scatter + pre-sort: srcS/dstS/cS and bf16 attr rows (padded to 64 shorts) in sorted order
__global__ __launch_bounds__(256) void k_scatter2(
    const int* __restrict__ ei, const float* __restrict__ ew,
    const float* __restrict__ attr, int* __restrict__ cursor,
    int* __restrict__ srcS, int* __restrict__ dstS,
    float* __restrict__ cS, unsigned short* __restrict__ attrS)
{
  int e = blockIdx.x * 256 + threadIdx.x;
  if (e >= E_NUM) return;
  int d = ei[E_NUM + e];
  int pos = atomicAdd(&cursor[d], 1);
  srcS[pos] = ei[e];
  dstS[pos] = d;
  cS[pos] = 0.5f * (__builtin_amdgcn_cosf(ew[e] * 0.05f) + 1.f);
  const float* rp = attr + (long)e * NG;
  unsigned short* op = attrS + (long)pos * 64;
  float2 v[25];
#pragma unroll
  for (int i = 0; i < 25; ++i) v[i] = *(const float2*)(rp + 2 * i);
#pragma unroll
  for (int c = 0; c < 8; ++c) {
    ushortx8 o;
#pragma unroll
    for (int j = 0; j < 8; ++j) {
      int k = c * 8 + j;
      o[j] = (k < NG) ? f2b((k & 1) ? v[k >> 1].y : v[k >> 1].x) : (unsigned short)0;
    }
    *(ushortx8*)(op + c * 8) = o;
  }
}

// ---------------- node GEMM (bf16 MFMA, 128-node blocks) ----------------
__global__ __launch_bounds__(256) void k_mfma_gemm(
    const float* __restrict__ X, const float* __restrict__ Wm,
    const float* __restrict__ bias, float* __restrict__ out, int act, int nrows)
{
  __shared__ __attribute__((aligned(16))) unsigned short s_x[128 * 128];
  __shared__ __attribute__((aligned(16))) unsigned short s_w[128 * 128];
  const int tid = threadIdx.x;
  const int w = tid >> 6, lane = tid & 63, q = lane >> 4, n16 = lane & 15;
  const int base = blockIdx.x * 128;

  for (int c = tid; c < 128 * 16; c += 256) {
    int f = c >> 4, ch = c & 15;
    const float4* wp = (const float4*)(Wm + f * 128 + ch * 8);
    float4 v0 = wp[0], v1 = wp[1];
    ushortx8 v = { f2b(v0.x), f2b(v0.y), f2b(v0.z), f2b(v0.w),
                   f2b(v1.x), f2b(v1.y), f2b(v1.z), f2b(v1.w) };
    *(ushortx8*)&s_w[(f << 7) + ((ch ^ (f & 15)) << 3)] = v;
  }
  for (int c = tid; c < 128 * 16; c += 256) {
    int r = c >> 4, ch = c & 15;
    int n = base + r;
    float4 v0 = {0.f, 0.f, 0.f, 0.f}, v1 = v0;
    if (n < nrows) {
      const float4* xp = (const float4*)(X + (long)n * 128 + ch * 8);
      v0 = xp[0]; v1 = xp[1];
    }
    ushortx8 v = { f2b(v0.x), f2b(v0.y), f2b(v0.z), f2b(v0.w),
                   f2b(v1.x), f2b(v1.y), f2b(v1.z), f2b(v1.w) };
    *(ushortx8*)&s_x[(r << 7) + ((ch ^ (r & 15)) << 3)] = v;
  }
  __syncthreads();

  float bv[8];
#pragma unroll
  for (int t = 0; t < 8; ++t) bv[t] = bias ? bias[t * 16 + n16] : 0.f;

  bf16x8 a[2][4];
#pragma unroll
  for (int g = 0; g < 2; ++g) {
    int r = w * 32 + g * 16 + n16;
#pragma unroll
    for (int ks = 0; ks < 4; ++ks)
      a[g][ks] = *(const bf16x8*)&s_x[(r << 7) + (((ks * 4 + q) ^ (r & 15)) << 3)];
  }
#pragma unroll
  for (int t = 0; t < 8; ++t) {
    int f = t * 16 + n16;
    bf16x8 b[4];
#pragma unroll
    for (int ks = 0; ks < 4; ++ks)
      b[ks] = *(const bf16x8*)&s_w[(f << 7) + (((ks * 4 + q) ^ (f & 15)) << 3)];
#pragma unroll
    for (int g = 0; g < 2; ++g) {
      f32x4 acc = {0.f, 0.f, 0.f, 0.f};
#pragma unroll
      for (int ks = 0; ks < 4; ++ks)
        acc = __builtin_amdgcn_mfma_f32_16x16x32_bf16(a[g][ks], b[ks], acc, 0, 0, 0);
#pragma unroll
      for (int r = 0; r < 4; ++r) {
        int n = base + w * 32 + g * 16 + q * 4 + r;
        if (n < nrows) {
          float v = acc[r] + bv[t];
          if (act) v = sspf(v);
          out[(long)n * 128 + f] = v;
        }
      }
    }
  }
}

// ---------------- fused gemm2+gemm3: out = sspf(agg@W2^T+b2)@W3^T+b3 ----------------
__global__ __launch_bounds__(256, 2) void k_gemm23(
    const float* __restrict__ A, const float* __restrict__ W2,
    const float* __restrict__ B2, const float* __restrict__ W3,
    const float* __restrict__ B3, float* __restrict__ out, int nrows)
{
  __shared__ __attribute__((aligned(16))) unsigned short s_x[128 * 128];
  __shared__ __attribute__((aligned(16))) unsigned short s_w[128 * 128];
  const int tid = threadIdx.x;
  const int w = tid >> 6, lane = tid & 63, q = lane >> 4, n16 = lane & 15;
  const int base = blockIdx.x * 128;

  for (int c = tid; c < 128 * 16; c += 256) {
    int f = c >> 4, ch = c & 15;
    const float4* wp = (const float4*)(W2 + f * 128 + ch * 8);
    float4 v0 = wp[0], v1 = wp[1];
    ushortx8 v = { f2b(v0.x), f2b(v0.y), f2b(v0.z), f2b(v0.w),
                   f2b(v1.x), f2b(v1.y), f2b(v1.z), f2b(v1.w) };
    *(ushortx8*)&s_w[(f << 7) + ((ch ^ (f & 15)) << 3)] = v;
  }
  for (int c = tid; c < 128 * 16; c += 256) {
    int r = c >> 4, ch = c & 15;
    int n = base + r;
    float4 v0 = {0.f, 0.f, 0.f, 0.f}, v1 = v0;
    if (n < nrows) {
      const float4* xp = (const float4*)(A + (long)n * 128 + ch * 8);
      v0 = xp[0]; v1 = xp[1];
    }
    ushortx8 v = { f2b(v0.x), f2b(v0.y), f2b(v0.z), f2b(v0.w),
                   f2b(v1.x), f2b(v1.y), f2b(v1.z), f2b(v1.w) };
    *(ushortx8*)&s_x[(r << 7) + ((ch ^ (r & 15)) << 3)] = v;
  }
  __syncthreads();

  float b2v[8], b3v[8];
#pragma unroll
  for (int t = 0; t < 8; ++t) { b2v[t] = B2[t * 16 + n16]; b3v[t] = B3[t * 16 + n16]; }

  bf16x8 a[2][4];
#pragma unroll
  for (int g = 0; g < 2; ++g) {
    int r = w * 32 + g * 16 + n16;
#pragma unroll
    for (int ks = 0; ks < 4; ++ks)
      a[g][ks] = *(const bf16x8*)&s_x[(r << 7) + (((ks * 4 + q) ^ (r & 15)) << 3)];
  }
  float acc1[8][2][4];
#pragma unroll
  for (int t = 0; t < 8; ++t) {
    int f = t * 16 + n16;
    bf16x8 b[4];
#pragma unroll
    for (int ks = 0; ks < 4; ++ks)
      b[ks] = *(const bf16x8*)&s_w[(f << 7) + (((ks * 4 + q) ^ (f & 15)) << 3)];
#pragma unroll
    for (int g = 0; g < 2; ++g) {
      f32x4 acc = {0.f, 0.f, 0.f, 0.f};
#pragma unroll
      for (int ks = 0; ks < 4; ++ks)
        acc = __builtin_amdgcn_mfma_f32_16x16x32_bf16(a[g][ks], b[ks], acc, 0, 0, 0);
#pragma unroll
      for (int r = 0; r < 4; ++r) acc1[t][g][r] = acc[r];
    }
  }
  __syncthreads();   // all reads of s_x/s_w done

  // h2 = sspf(acc1 + b2) -> s_x (swizzled); restage s_w <- W3
#pragma unroll
  for (int t = 0; t < 8; ++t) {
    int f = t * 16 + n16;
#pragma unroll
    for (int g = 0; g < 2; ++g)
#pragma unroll
      for (int r = 0; r < 4; ++r) {
        int row = w * 32 + g * 16 + q * 4 + r;
        s_x[(row << 7) + (((f >> 3) ^ (row & 15)) << 3) + (f & 7)] =
            f2b(sspf(acc1[t][g][r] + b2v[t]));
      }
  }
  for (int c = tid; c < 128 * 16; c += 256) {
    int f = c >> 4, ch = c & 15;
    const float4* wp = (const float4*)(W3 + f * 128 + ch * 8);
    float4 v0 = wp[0], v1 = wp[1];
    ushortx8 v = { f2b(v0.x), f2b(v0.y), f2b(v0.z), f2b(v0.w),
                   f2b(v1.x), f2b(v1.y), f2b(v1.z), f2b(v1.w) };
    *(ushortx8*)&s_w[(f << 7) + ((ch ^ (f & 15)) << 3)] = v;
  }
  __syncthreads();

#pragma unroll
  for (int g = 0; g < 2; ++g) {
    int r = w * 32 + g * 16 + n16;
#pragma unroll
    for (int ks = 0; ks < 4; ++ks)
      a[g][ks] = *(const bf16x8*)&s_x[(r << 7) + (((ks * 4 + q) ^ (r & 15)) << 3)];
  }
#pragma unroll
  for (int t = 0; t < 8; ++t) {
    int f = t * 16 + n16;
    bf16x8 b[4];
#pragma unroll
    for (int ks = 0; ks < 4; ++ks)
      b[ks] = *(const bf16x8*)&s_w[(f << 7) + (((ks * 4 + q) ^ (f & 15)) << 3)];
#pragma unroll
    for (int g = 0; g < 2; ++g) {
      f32x4 acc = {0.f, 0.f, 0.f, 0.f};
#pragma unroll
      for (int ks = 0; ks < 4; ++ks)
        acc = __builtin_amdgcn_mfma_f32_16x16x32_bf16(a[g][ks], b[ks], acc, 0, 0, 0);
#pragma unroll
      for (int r = 0; r < 4; ++r) {
        int n = base + w * 32 + g * 16 + q * 4 + r;
        if (n < nrows) out[(long)n * 128 + f] = acc[r] + b3v[t];
      }
    }
  }
}

// ---------------- fused edge MLP + aggregation, software-pipelined ----------------
// mode 1: tiles of 16 sorted positions. Carried across iterations: attr bf16 A-frags
//         (sequential attrS) and src indices (SGPR). h-row gathers issued at tile start
//         so latency hides under layer-1/2 MFMAs. Segmented flush into agg.
// mode 0: fallback: raw edge order, f32 attr, per-edge atomicAdd.
__global__ __launch_bounds__(256, 3) void k_edge_agg(
    const float* __restrict__ attr, const int* __restrict__ ei,
    const float* __restrict__ ew, const float* __restrict__ w1,
    const float* __restrict__ b1, const float* __restrict__ w2,
    const float* __restrict__ b2, const float* __restrict__ h,
    const int* __restrict__ srcS, const int* __restrict__ dstS,
    const float* __restrict__ cS, const unsigned short* __restrict__ attrS,
    float* __restrict__ agg, int mode)
{
  __shared__ __attribute__((aligned(16))) unsigned short s_w2[128 * 128];     // 32 KB, swizzled
  __shared__ __attribute__((aligned(16))) unsigned short s_scr[4 * 16 * 136]; // 4 waves x 16 rows

  const int tid  = threadIdx.x;
  const int w    = tid >> 6;
  const int lane = tid & 63;
  const int q    = lane >> 4;
  const int n16  = lane & 15;

  for (int i = tid; i < 128 * 128; i += 256) {
    int f = i >> 7, k = i & 127;
    int pos = (f << 7) + ((((k >> 3) ^ (f & 15)) << 3)) + (k & 7);
    s_w2[pos] = f2b(w2[i]);
  }
  bf16x8 w1A[8], w1B[8];
#pragma unroll
  for (int t = 0; t < 8; ++t) {
    int f = t * 16 + n16;
    const float* row = w1 + f * NG;
    union { ushortx8 u; bf16x8 b; } ua, ub;
#pragma unroll
    for (int j = 0; j < 8; ++j) ua.u[j] = f2b(row[q * 8 + j]);
#pragma unroll
    for (int j = 0; j < 8; ++j) { int k = 32 + q * 8 + j; ub.u[j] = (k < NG) ? f2b(row[k]) : (unsigned short)0; }
    w1A[t] = ua.b; w1B[t] = ub.b;
  }
  float b1v[8], b2v[8];
#pragma unroll
  for (int t = 0; t < 8; ++t) {
    b1v[t] = b1[t * 16 + n16];
    b2v[t] = b2[t * 16 + n16];
  }
  __syncthreads();  // s_w2 ready — only block barrier

  unsigned short* scr = s_scr + w * (16 * 136);
  const int nwaves = EDGE_BLOCKS * 4;
  const int gw = blockIdx.x * 4 + w;

  if (mode == 1) {
    // ---- prologue: tile0 state ----
    int tile = gw;
    bf16x8 uaC, ubC;
    int svs[16];
    {
      const long e0 = (long)tile * 16;
      uaC = *(const bf16x8*)(attrS + (e0 + n16) * 64 + q * 8);
      ubC = *(const bf16x8*)(attrS + (e0 + n16) * 64 + 32 + q * 8);
#pragma unroll
      for (int i = 0; i < 16; ++i) svs[i] = __builtin_amdgcn_readfirstlane(srcS[e0 + i]);
    }

    for (; tile < NTW; tile += nwaves) {
      const int e0 = tile * 16;
      const int tn = tile + nwaves;
      const bool hasnext = (tn < NTW);

      // 1) issue current-tile h gathers (latency hides under MFMAs below)
      float2 hv[16];
#pragma unroll
      for (int i = 0; i < 16; ++i)
        hv[i] = *(const float2*)(h + (long)svs[i] * 128 + (lane << 1));
      float cvv[4];
#pragma unroll
      for (int r = 0; r < 4; ++r) cvv[r] = cS[e0 + q * 4 + r];
      // prefetch next tile's attr frags + src indices
      bf16x8 uaN = uaC, ubN = ubC;
      int svN[16];
#pragma unroll
      for (int i = 0; i < 16; ++i) svN[i] = 0;
      if (hasnext) {
        const long en = (long)tn * 16;
        uaN = *(const bf16x8*)(attrS + (en + n16) * 64 + q * 8);
        ubN = *(const bf16x8*)(attrS + (en + n16) * 64 + 32 + q * 8);
#pragma unroll
        for (int i = 0; i < 16; ++i) svN[i] = srcS[en + i];
      }

      // 2) layer 1 -> h_e into wave-private scratch
#pragma unroll
      for (int t = 0; t < 8; ++t) {
        f32x4 acc = {0.f, 0.f, 0.f, 0.f};
        acc = __builtin_amdgcn_mfma_f32_16x16x32_bf16(uaC, w1A[t], acc, 0, 0, 0);
        acc = __builtin_amdgcn_mfma_f32_16x16x32_bf16(ubC, w1B[t], acc, 0, 0, 0);
        int f = t * 16 + n16;
#pragma unroll
        for (int r = 0; r < 4; ++r) {
          int row = q * 4 + r;
          scr[row * 136 + f] = f2b(sspf(acc[r] + b1v[t]));
        }
      }
      __builtin_amdgcn_wave_barrier();

      bf16x8 a2f[4];
#pragma unroll
      for (int ks = 0; ks < 4; ++ks)
        a2f[ks] = *(const bf16x8*)&scr[n16 * 136 + ks * 32 + q * 8];
      __builtin_amdgcn_wave_barrier();

      // 4) layer 2 -> W*C into scratch
#pragma unroll
      for (int t = 0; t < 8; ++t) {
        int f = t * 16 + n16;
        f32x4 acc = {0.f, 0.f, 0.f, 0.f};
#pragma unroll
        for (int ks = 0; ks < 4; ++ks) {
          bf16x8 bb = *(const bf16x8*)&s_w2[(f << 7) + (((ks * 4 + q) ^ (f & 15)) << 3)];
          acc = __builtin_amdgcn_mfma_f32_16x16x32_bf16(a2f[ks], bb, acc, 0, 0, 0);
        }
#pragma unroll
        for (int r = 0; r < 4; ++r) {
          int row = q * 4 + r;
          scr[row * 136 + f] = f2b((acc[r] + b2v[t]) * cvv[r]);
        }
      }
      __builtin_amdgcn_wave_barrier();

      // 5) segmented aggregation using preloaded hv
      int dvv[16];
#pragma unroll
      for (int i = 0; i < 16; ++i) dvv[i] = dstS[e0 + i];   // one cache line, broadcast
      int dcur = -1, rowstart = 0;
      float ax = 0.f, ay = 0.f;
#pragma unroll
      for (int i = 0; i < 16; ++i) {
        int dv = __builtin_amdgcn_readfirstlane(dvv[i]);
        if (dv != dcur) {
          if (dcur >= 0) {
            float* ap = agg + (long)dcur * 128 + (lane << 1);
            if (rowstart == 0) { atomicAdd(ap, ax); atomicAdd(ap + 1, ay); }
            else { float2 o; o.x = ax; o.y = ay; *(float2*)ap = o; }  // interior run: exclusive
          }
          dcur = dv; ax = 0.f; ay = 0.f; rowstart = i;
        }
        unsigned wp = *(const unsigned*)&scr[i * 136 + (lane << 1)];
        ax = fmaf(hv[i].x, b2f((unsigned short)(wp & 0xffffu)), ax);
        ay = fmaf(hv[i].y, b2f((unsigned short)(wp >> 16)), ay);
      }
      {  // final run touches tile boundary -> atomic
        float* ap = agg + (long)dcur * 128 + (lane << 1);
        atomicAdd(ap, ax); atomicAdd(ap + 1, ay);
      }
      __builtin_amdgcn_wave_barrier();  // scr reused next tile

      // 6) rotate pipeline state
      if (hasnext) {
#pragma unroll
        for (int i = 0; i < 16; ++i) svs[i] = __builtin_amdgcn_readfirstlane(svN[i]);
        uaC = uaN; ubC = ubN;
      }
    }
  } else {
    // ---------- mode 0 fallback: natural order, per-edge atomics ----------
    for (int tile = gw; tile < NTW; tile += nwaves) {
      const int e0 = tile * 16;
      const int er = e0 + n16;
      const float* rp = attr + (long)er * NG;

      float2 p0 = *(const float2*)(rp + q * 8);
      float2 p1 = *(const float2*)(rp + q * 8 + 2);
      float2 p2 = *(const float2*)(rp + q * 8 + 4);
      float2 p3 = *(const float2*)(rp + q * 8 + 6);
      float2 p4 = {0.f, 0.f}, p5 = {0.f, 0.f}, p6 = {0.f, 0.f}, p7 = {0.f, 0.f};
      if (q < 2) {
        const float* rp2 = rp + 32 + q * 8;
        p4 = *(const float2*)(rp2);
        p5 = *(const float2*)(rp2 + 2);
        p6 = *(const float2*)(rp2 + 4);
        p7 = *(const float2*)(rp2 + 6);
      } else if (q == 2) {
        p4 = *(const float2*)(rp + 48);
      }
      union { ushortx8 u; bf16x8 b; } ua, ub;
      ua.u[0] = f2b(p0.x); ua.u[1] = f2b(p0.y); ua.u[2] = f2b(p1.x); ua.u[3] = f2b(p1.y);
      ua.u[4] = f2b(p2.x); ua.u[5] = f2b(p2.y); ua.u[6] = f2b(p3.x); ua.u[7] = f2b(p3.y);
      ub.u[0] = f2b(p4.x); ub.u[1] = f2b(p4.y); ub.u[2] = f2b(p5.x); ub.u[3] = f2b(p5.y);
      ub.u[4] = f2b(p6.x); ub.u[5] = f2b(p6.y); ub.u[6] = f2b(p7.x); ub.u[7] = f2b(p7.y);

#pragma unroll
      for (int t = 0; t < 8; ++t) {
        f32x4 acc = {0.f, 0.f, 0.f, 0.f};
        acc = __builtin_amdgcn_mfma_f32_16x16x32_bf16(ua.b, w1A[t], acc, 0, 0, 0);
        acc = __builtin_amdgcn_mfma_f32_16x16x32_bf16(ub.b, w1B[t], acc, 0, 0, 0);
        int f = t * 16 + n16;
#pragma unroll
        for (int r = 0; r < 4; ++r) {
          int row = q * 4 + r;
          scr[row * 136 + f] = f2b(sspf(acc[r] + b1v[t]));
        }
      }
      __builtin_amdgcn_wave_barrier();

      bf16x8 a2f[4];
#pragma unroll
      for (int ks = 0; ks < 4; ++ks)
        a2f[ks] = *(const bf16x8*)&scr[n16 * 136 + ks * 32 + q * 8];
      __builtin_amdgcn_wave_barrier();

      float cvv[4];
      int srcv[4], dstv[4];
#pragma unroll
      for (int r = 0; r < 4; ++r) {
        cvv[r] = 0.5f * (__builtin_amdgcn_cosf(ew[e0 + q * 4 + r] * 0.05f) + 1.f);
        srcv[r] = ei[e0 + q * 4 + r];
        dstv[r] = ei[E_NUM + e0 + q * 4 + r];
      }

#pragma unroll
      for (int t = 0; t < 8; ++t) {
        int f = t * 16 + n16;
        f32x4 acc = {0.f, 0.f, 0.f, 0.f};
#pragma unroll
        for (int ks = 0; ks < 4; ++ks) {
          bf16x8 bb = *(const bf16x8*)&s_w2[(f << 7) + (((ks * 4 + q) ^ (f & 15)) << 3)];
          acc = __builtin_amdgcn_mfma_f32_16x16x32_bf16(a2f[ks], bb, acc, 0, 0, 0);
        }
#pragma unroll
        for (int r = 0; r < 4; ++r) {
          float msg = h[(long)srcv[r] * 128 + f] * (acc[r] + b2v[t]) * cvv[r];
          atomicAdd(&agg[(long)dstv[r] * 128 + f], msg);
        }
      }
      __builtin_amdgcn_wave_barrier();
    }
  }
}

extern "C" void kernel_launch(void* const* d_in, const int* in_sizes, int n_in,
                              void* d_out, int out_size, void* d_ws, size_t ws_size,
                              hipStream_t stream) {
  const float* x     = (const float*)d_in[0];
  const int*   ei    = (const int*)  d_in[1];
  const float* ew    = (const float*)d_in[2];
  const float* attr  = (const float*)d_in[3];
  const float* w1    = (const float*)d_in[4];
  const float* b1    = (const float*)d_in[5];
  const float* w2    = (const float*)d_in[6];
  const float* b2    = (const float*)d_in[7];
  const float* lin1w = (const float*)d_in[8];
  const float* lin2w = (const float*)d_in[9];
  const float* lin2b = (const float*)d_in[10];
  const float* linw  = (const float*)d_in[11];
  const float* linb  = (const float*)d_in[12];
  float* out = (float*)d_out;

  // workspace layout
  char* base = (char*)d_ws;
  float* agg    = (float*)base;                               // NN*128 f32
  float* h      = agg + (size_t)NN * 128;                     // NN*128 f32
  int*   counts = (int*)(h + (size_t)NN * 128);               // NN
  int*   cursor = counts + NN;                                // NN
  int*   srcS   = cursor + NN;                                // E
  int*   dstS   = srcS + E_NUM;                               // E
  float* cS     = (float*)(dstS + E_NUM);                     // E
  size_t head   = (size_t)((char*)(cS + E_NUM) - base);
  size_t aoff   = (head + 255) & ~(size_t)255;                // 256-B align
  unsigned short* attrS = (unsigned short*)(base + aoff);     // E*64 bf16 (padded rows)
  size_t need   = aoff + (size_t)E_NUM * 64 * sizeof(unsigned short);
  const int mode = (ws_size >= need) ? 1 : 0;

  const int gemm_grid = (NN + 127) / 128;
  (void)hipMemsetAsync(agg, 0, (size_t)NN * 128 * sizeof(float), stream);
  if (mode == 1) {
    (void)hipMemsetAsync(counts, 0, (size_t)NN * sizeof(int), stream);
    k_hist<<<(E_NUM + 255) / 256, 256, 0, stream>>>(ei, counts);
    k_scan<<<1, 1024, 0, stream>>>(counts, cursor);
    k_scatter2<<<(E_NUM + 255) / 256, 256, 0, stream>>>(ei, ew, attr, cursor,
                                                        srcS, dstS, cS, attrS);
  }
  k_mfma_gemm<<<gemm_grid, 256, 0, stream>>>(x, lin1w, nullptr, h, 0, NN);
  k_edge_agg<<<EDGE_BLOCKS, 256, 0, stream>>>(attr, ei, ew, w1, b1, w2, b2, h,
                                              srcS, dstS, cS, attrS, agg, mode);
  k_gemm23<<<gemm_grid, 256, 0, stream>>>(agg, lin2w, lin2b, linw, linb, out, NN);
}

// Round 3
// 611.483 us; speedup vs baseline: 1.1642x; 1.1642x over previous
//
#include <hip/hip_runtime.h>
#include <hip/hip_bf16.h>
#include <math.h>

#define E_NUM 800000
#define NN 50000
#define NG 50
#define NTW (E_NUM / 16)        // 16-edge wave-tiles
#define EDGE_BLOCKS 512         // 2 blocks/CU (512 threads, 66 KB LDS)

typedef __bf16 bf16x8 __attribute__((ext_vector_type(8)));
typedef float f32x4 __attribute__((ext_vector_type(4)));
typedef unsigned short ushortx8 __attribute__((ext_vector_type(8)));

// native f32->bf16 (RNE)
__device__ __forceinline__ unsigned short f2b(float f) {
  union { __bf16 h; unsigned short u; } v; v.h = (__bf16)f; return v.u;
}
__device__ __forceinline__ float b2f(unsigned short u) {
  union { unsigned u; float f; } v; v.u = ((unsigned)u) << 16; return v.f;
}
// shifted softplus via hw exp2/log2
__device__ __forceinline__ float sspf(float v) {
  float e = __builtin_amdgcn_exp2f(-1.4426950408889634f * fabsf(v));
  return fmaxf(v, 0.f) + 0.6931471805599453f * __builtin_amdgcn_logf(fmaf(0.5f, e, 0.5f));
}

// ---------------- counting sort by dst ----------------
__global__ __launch_bounds__(256) void k_hist(const int* __restrict__ ei, int* __restrict__ counts) {
  int e = blockIdx.x * 256 + threadIdx.x;
  if (e < E_NUM) atomicAdd(&counts[ei[E_NUM + e]], 1);
}

__global__ __launch_bounds__(1024) void k_scan(const int* __restrict__ counts,
                                               int* __restrict__ cursor) {
  __shared__ int tot[1024];
  const int t = threadIdx.x;
  const int C = (NN + 1023) >> 10;  // 49
  int lo = t * C, hi = lo + C; if (hi > NN) hi = NN; if (lo > NN) lo = NN;
  int s = 0;
  for (int i = lo; i < hi; ++i) s += counts[i];
  tot[t] = s;
  __syncthreads();
  int mine = s;
  for (int o = 1; o < 1024; o <<= 1) {
    int v = (t >= o) ? tot[t - o] : 0;
    __syncthreads();
    tot[t] += v;
    __syncthreads();
  }
  int run = tot[t] - mine;
  for (int i = lo; i < hi; ++i) { int c = counts[i]; cursor[i] = run; run += c; }
}

// scatter + pre-sort: srcS/dstS/cS and bf16 attr rows (padded to 64 shorts) in sorted order
__global__ __launch_bounds__(256) void k_scatter2(
    const int* __restrict__ ei, const float* __restrict__ ew,
    const float* __restrict__ attr, int* __restrict__ cursor,
    int* __restrict__ srcS, int* __restrict__ dstS,
    float* __restrict__ cS, unsigned short* __restrict__ attrS)
{
  int e = blockIdx.x * 256 + threadIdx.x;
  if (e >= E_NUM) return;
  int d = ei[E_NUM + e];
  int pos = atomicAdd(&cursor[d], 1);
  srcS[pos] = ei[e];
  dstS[pos] = d;
  cS[pos] = 0.5f * (__builtin_amdgcn_cosf(ew[e] * 0.05f) + 1.f);
  const float* rp = attr + (long)e * NG;
  unsigned short* op = attrS + (long)pos * 64;
  float2 v[25];
#pragma unroll
  for (int i = 0; i < 25; ++i) v[i] = *(const float2*)(rp + 2 * i);
#pragma unroll
  for (int c = 0; c < 8; ++c) {
    ushortx8 o;
#pragma unroll
    for (int j = 0; j < 8; ++j) {
      int k = c * 8 + j;
      o[j] = (k < NG) ? f2b((k & 1) ? v[k >> 1].y : v[k >> 1].x) : (unsigned short)0;
    }
    *(ushortx8*)(op + c * 8) = o;
  }
}

// ---------------- node GEMM (bf16 MFMA, 128-node blocks) ----------------
__global__ __launch_bounds__(256) void k_mfma_gemm(
    const float* __restrict__ X, const float* __restrict__ Wm,
    const float* __restrict__ bias, float* __restrict__ out, int act, int nrows)
{
  __shared__ __attribute__((aligned(16))) unsigned short s_x[128 * 128];
  __shared__ __attribute__((aligned(16))) unsigned short s_w[128 * 128];
  const int tid = threadIdx.x;
  const int w = tid >> 6, lane = tid & 63, q = lane >> 4, n16 = lane & 15;
  const int base = blockIdx.x * 128;

  for (int c = tid; c < 128 * 16; c += 256) {
    int f = c >> 4, ch = c & 15;
    const float4* wp = (const float4*)(Wm + f * 128 + ch * 8);
    float4 v0 = wp[0], v1 = wp[1];
    ushortx8 v = { f2b(v0.x), f2b(v0.y), f2b(v0.z), f2b(v0.w),
                   f2b(v1.x), f2b(v1.y), f2b(v1.z), f2b(v1.w) };
    *(ushortx8*)&s_w[(f << 7) + ((ch ^ (f & 15)) << 3)] = v;
  }
  for (int c = tid; c < 128 * 16; c += 256) {
    int r = c >> 4, ch = c & 15;
    int n = base + r;
    float4 v0 = {0.f, 0.f, 0.f, 0.f}, v1 = v0;
    if (n < nrows) {
      const float4* xp = (const float4*)(X + (long)n * 128 + ch * 8);
      v0 = xp[0]; v1 = xp[1];
    }
    ushortx8 v = { f2b(v0.x), f2b(v0.y), f2b(v0.z), f2b(v0.w),
                   f2b(v1.x), f2b(v1.y), f2b(v1.z), f2b(v1.w) };
    *(ushortx8*)&s_x[(r << 7) + ((ch ^ (r & 15)) << 3)] = v;
  }
  __syncthreads();

  float bv[8];
#pragma unroll
  for (int t = 0; t < 8; ++t) bv[t] = bias ? bias[t * 16 + n16] : 0.f;

  bf16x8 a[2][4];
#pragma unroll
  for (int g = 0; g < 2; ++g) {
    int r = w * 32 + g * 16 + n16;
#pragma unroll
    for (int ks = 0; ks < 4; ++ks)
      a[g][ks] = *(const bf16x8*)&s_x[(r << 7) + (((ks * 4 + q) ^ (r & 15)) << 3)];
  }
#pragma unroll
  for (int t = 0; t < 8; ++t) {
    int f = t * 16 + n16;
    bf16x8 b[4];
#pragma unroll
    for (int ks = 0; ks < 4; ++ks)
      b[ks] = *(const bf16x8*)&s_w[(f << 7) + (((ks * 4 + q) ^ (f & 15)) << 3)];
#pragma unroll
    for (int g = 0; g < 2; ++g) {
      f32x4 acc = {0.f, 0.f, 0.f, 0.f};
#pragma unroll
      for (int ks = 0; ks < 4; ++ks)
        acc = __builtin_amdgcn_mfma_f32_16x16x32_bf16(a[g][ks], b[ks], acc, 0, 0, 0);
#pragma unroll
      for (int r = 0; r < 4; ++r) {
        int n = base + w * 32 + g * 16 + q * 4 + r;
        if (n < nrows) {
          float v = acc[r] + bv[t];
          if (act) v = sspf(v);
          out[(long)n * 128 + f] = v;
        }
      }
    }
  }
}

// ---------------- fused gemm2+gemm3: out = sspf(agg@W2^T+b2)@W3^T+b3 ----------------
__global__ __launch_bounds__(256, 2) void k_gemm23(
    const float* __restrict__ A, const float* __restrict__ W2,
    const float* __restrict__ B2, const float* __restrict__ W3,
    const float* __restrict__ B3, float* __restrict__ out, int nrows)
{
  __shared__ __attribute__((aligned(16))) unsigned short s_x[128 * 128];
  __shared__ __attribute__((aligned(16))) unsigned short s_w[128 * 128];
  const int tid = threadIdx.x;
  const int w = tid >> 6, lane = tid & 63, q = lane >> 4, n16 = lane & 15;
  const int base = blockIdx.x * 128;

  for (int c = tid; c < 128 * 16; c += 256) {
    int f = c >> 4, ch = c & 15;
    const float4* wp = (const float4*)(W2 + f * 128 + ch * 8);
    float4 v0 = wp[0], v1 = wp[1];
    ushortx8 v = { f2b(v0.x), f2b(v0.y), f2b(v0.z), f2b(v0.w),
                   f2b(v1.x), f2b(v1.y), f2b(v1.z), f2b(v1.w) };
    *(ushortx8*)&s_w[(f << 7) + ((ch ^ (f & 15)) << 3)] = v;
  }
  for (int c = tid; c < 128 * 16; c += 256) {
    int r = c >> 4, ch = c & 15;
    int n = base + r;
    float4 v0 = {0.f, 0.f, 0.f, 0.f}, v1 = v0;
    if (n < nrows) {
      const float4* xp = (const float4*)(A + (long)n * 128 + ch * 8);
      v0 = xp[0]; v1 = xp[1];
    }
    ushortx8 v = { f2b(v0.x), f2b(v0.y), f2b(v0.z), f2b(v0.w),
                   f2b(v1.x), f2b(v1.y), f2b(v1.z), f2b(v1.w) };
    *(ushortx8*)&s_x[(r << 7) + ((ch ^ (r & 15)) << 3)] = v;
  }
  __syncthreads();

  float b2v[8], b3v[8];
#pragma unroll
  for (int t = 0; t < 8; ++t) { b2v[t] = B2[t * 16 + n16]; b3v[t] = B3[t * 16 + n16]; }

  bf16x8 a[2][4];
#pragma unroll
  for (int g = 0; g < 2; ++g) {
    int r = w * 32 + g * 16 + n16;
#pragma unroll
    for (int ks = 0; ks < 4; ++ks)
      a[g][ks] = *(const bf16x8*)&s_x[(r << 7) + (((ks * 4 + q) ^ (r & 15)) << 3)];
  }
  float acc1[8][2][4];
#pragma unroll
  for (int t = 0; t < 8; ++t) {
    int f = t * 16 + n16;
    bf16x8 b[4];
#pragma unroll
    for (int ks = 0; ks < 4; ++ks)
      b[ks] = *(const bf16x8*)&s_w[(f << 7) + (((ks * 4 + q) ^ (f & 15)) << 3)];
#pragma unroll
    for (int g = 0; g < 2; ++g) {
      f32x4 acc = {0.f, 0.f, 0.f, 0.f};
#pragma unroll
      for (int ks = 0; ks < 4; ++ks)
        acc = __builtin_amdgcn_mfma_f32_16x16x32_bf16(a[g][ks], b[ks], acc, 0, 0, 0);
#pragma unroll
      for (int r = 0; r < 4; ++r) acc1[t][g][r] = acc[r];
    }
  }
  __syncthreads();   // all reads of s_x/s_w done

  // h2 = sspf(acc1 + b2) -> s_x (swizzled); restage s_w <- W3
#pragma unroll
  for (int t = 0; t < 8; ++t) {
    int f = t * 16 + n16;
#pragma unroll
    for (int g = 0; g < 2; ++g)
#pragma unroll
      for (int r = 0; r < 4; ++r) {
        int row = w * 32 + g * 16 + q * 4 + r;
        s_x[(row << 7) + (((f >> 3) ^ (row & 15)) << 3) + (f & 7)] =
            f2b(sspf(acc1[t][g][r] + b2v[t]));
      }
  }
  for (int c = tid; c < 128 * 16; c += 256) {
    int f = c >> 4, ch = c & 15;
    const float4* wp = (const float4*)(W3 + f * 128 + ch * 8);
    float4 v0 = wp[0], v1 = wp[1];
    ushortx8 v = { f2b(v0.x), f2b(v0.y), f2b(v0.z), f2b(v0.w),
                   f2b(v1.x), f2b(v1.y), f2b(v1.z), f2b(v1.w) };
    *(ushortx8*)&s_w[(f << 7) + ((ch ^ (f & 15)) << 3)] = v;
  }
  __syncthreads();

#pragma unroll
  for (int g = 0; g < 2; ++g) {
    int r = w * 32 + g * 16 + n16;
#pragma unroll
    for (int ks = 0; ks < 4; ++ks)
      a[g][ks] = *(const bf16x8*)&s_x[(r << 7) + (((ks * 4 + q) ^ (r & 15)) << 3)];
  }
#pragma unroll
  for (int t = 0; t < 8; ++t) {
    int f = t * 16 + n16;
    bf16x8 b[4];
#pragma unroll
    for (int ks = 0; ks < 4; ++ks)
      b[ks] = *(const bf16x8*)&s_w[(f << 7) + (((ks * 4 + q) ^ (f & 15)) << 3)];
#pragma unroll
    for (int g = 0; g < 2; ++g) {
      f32x4 acc = {0.f, 0.f, 0.f, 0.f};
#pragma unroll
      for (int ks = 0; ks < 4; ++ks)
        acc = __builtin_amdgcn_mfma_f32_16x16x32_bf16(a[g][ks], b[ks], acc, 0, 0, 0);
#pragma unroll
      for (int r = 0; r < 4; ++r) {
        int n = base + w * 32 + g * 16 + q * 4 + r;
        if (n < nrows) out[(long)n * 128 + f] = acc[r] + b3v[t];
      }
    }
  }
}

// ---------------- fused edge MLP + aggregation (512 threads, 2 blocks/CU) ----------------
// mode 1: tiles of 16 sorted positions. attrS sequential bf16 A-frags (next-tile frags
//         prefetched, 8 VGPRs carried). h gathers 8-at-a-time inside aggregation phase
//         (short liveness — round-2 spill lesson). Segmented flush into agg.
// mode 0: fallback: raw edge order, f32 attr, per-edge atomicAdd.
__global__ __launch_bounds__(512, 4) void k_edge_agg(
    const float* __restrict__ attr, const int* __restrict__ ei,
    const float* __restrict__ ew, const float* __restrict__ w1,
    const float* __restrict__ b1, const float* __restrict__ w2,
    const float* __restrict__ b2, const float* __restrict__ h,
    const int* __restrict__ srcS, const int* __restrict__ dstS,
    const float* __restrict__ cS, const unsigned short* __restrict__ attrS,
    float* __restrict__ agg, int mode)
{
  __shared__ __attribute__((aligned(16))) unsigned short s_w2[128 * 128];     // 32 KB, swizzled
  __shared__ __attribute__((aligned(16))) unsigned short s_scr[8 * 16 * 136]; // 8 waves x 16 rows

  const int tid  = threadIdx.x;
  const int w    = tid >> 6;
  const int lane = tid & 63;
  const int q    = lane >> 4;
  const int n16  = lane & 15;

  for (int i = tid; i < 128 * 128; i += 512) {
    int f = i >> 7, k = i & 127;
    int pos = (f << 7) + ((((k >> 3) ^ (f & 15)) << 3)) + (k & 7);
    s_w2[pos] = f2b(w2[i]);
  }
  bf16x8 w1A[8], w1B[8];
#pragma unroll
  for (int t = 0; t < 8; ++t) {
    int f = t * 16 + n16;
    const float* row = w1 + f * NG;
    union { ushortx8 u; bf16x8 b; } ua, ub;
#pragma unroll
    for (int j = 0; j < 8; ++j) ua.u[j] = f2b(row[q * 8 + j]);
#pragma unroll
    for (int j = 0; j < 8; ++j) { int k = 32 + q * 8 + j; ub.u[j] = (k < NG) ? f2b(row[k]) : (unsigned short)0; }
    w1A[t] = ua.b; w1B[t] = ub.b;
  }
  float b1v[8], b2v[8];
#pragma unroll
  for (int t = 0; t < 8; ++t) {
    b1v[t] = b1[t * 16 + n16];
    b2v[t] = b2[t * 16 + n16];
  }
  __syncthreads();  // s_w2 ready — only block barrier

  unsigned short* scr = s_scr + w * (16 * 136);
  const int nwaves = EDGE_BLOCKS * 8;
  const int gw = blockIdx.x * 8 + w;

  if (mode == 1) {
    // prologue: first tile's attr fragments (address is tile-linear, no dependency)
    bf16x8 uaN, ubN;
    {
      const long e0 = (long)gw * 16;
      uaN = *(const bf16x8*)(attrS + (e0 + n16) * 64 + q * 8);
      ubN = *(const bf16x8*)(attrS + (e0 + n16) * 64 + 32 + q * 8);
    }

    for (int tile = gw; tile < NTW; tile += nwaves) {
      const int e0 = tile * 16;
      bf16x8 uaC = uaN, ubC = ubN;

      // layer 1 -> h_e into wave-private scratch
#pragma unroll
      for (int t = 0; t < 8; ++t) {
        f32x4 acc = {0.f, 0.f, 0.f, 0.f};
        acc = __builtin_amdgcn_mfma_f32_16x16x32_bf16(uaC, w1A[t], acc, 0, 0, 0);
        acc = __builtin_amdgcn_mfma_f32_16x16x32_bf16(ubC, w1B[t], acc, 0, 0, 0);
        int f = t * 16 + n16;
#pragma unroll
        for (int r = 0; r < 4; ++r) {
          int row = q * 4 + r;
          scr[row * 136 + f] = f2b(sspf(acc[r] + b1v[t]));
        }
      }
      __builtin_amdgcn_wave_barrier();

      bf16x8 a2f[4];
#pragma unroll
      for (int ks = 0; ks < 4; ++ks)
        a2f[ks] = *(const bf16x8*)&scr[n16 * 136 + ks * 32 + q * 8];
      __builtin_amdgcn_wave_barrier();

      // prefetch next tile's attr fragments (latency covered by layer 2 + aggregation)
      {
        const int tn = tile + nwaves;
        if (tn < NTW) {
          const long en = (long)tn * 16;
          uaN = *(const bf16x8*)(attrS + (en + n16) * 64 + q * 8);
          ubN = *(const bf16x8*)(attrS + (en + n16) * 64 + 32 + q * 8);
        }
      }

      // cutoff factors (short liveness: layer-2 epilogue only)
      float cvv[4];
#pragma unroll
      for (int r = 0; r < 4; ++r) cvv[r] = cS[e0 + q * 4 + r];

      // layer 2 -> W*C into scratch
#pragma unroll
      for (int t = 0; t < 8; ++t) {
        int f = t * 16 + n16;
        f32x4 acc = {0.f, 0.f, 0.f, 0.f};
#pragma unroll
        for (int ks = 0; ks < 4; ++ks) {
          bf16x8 bb = *(const bf16x8*)&s_w2[(f << 7) + (((ks * 4 + q) ^ (f & 15)) << 3)];
          acc = __builtin_amdgcn_mfma_f32_16x16x32_bf16(a2f[ks], bb, acc, 0, 0, 0);
        }
#pragma unroll
        for (int r = 0; r < 4; ++r) {
          int row = q * 4 + r;
          scr[row * 136 + f] = f2b((acc[r] + b2v[t]) * cvv[r]);
        }
      }
      __builtin_amdgcn_wave_barrier();

      // segmented aggregation: msg[row] = h[srcS] * W, summed per dst run
      int dcur = -1, rowstart = 0;
      float ax = 0.f, ay = 0.f;
#pragma unroll
      for (int hf = 0; hf < 2; ++hf) {
        int dv[8]; float2 hv[8];
#pragma unroll
        for (int i = 0; i < 8; ++i) {
          int pos = e0 + hf * 8 + i;
          dv[i] = __builtin_amdgcn_readfirstlane(dstS[pos]);
          int sv = __builtin_amdgcn_readfirstlane(srcS[pos]);
          hv[i] = *(const float2*)(h + (long)sv * 128 + (lane << 1));
        }
#pragma unroll
        for (int i = 0; i < 8; ++i) {
          int row = hf * 8 + i;
          if (dv[i] != dcur) {
            if (dcur >= 0) {
              float* ap = agg + (long)dcur * 128 + (lane << 1);
              if (rowstart == 0) { atomicAdd(ap, ax); atomicAdd(ap + 1, ay); }
              else { float2 o; o.x = ax; o.y = ay; *(float2*)ap = o; }  // interior run: exclusive
            }
            dcur = dv[i]; ax = 0.f; ay = 0.f; rowstart = row;
          }
          unsigned wp = *(const unsigned*)&scr[row * 136 + (lane << 1)];
          ax = fmaf(hv[i].x, b2f((unsigned short)(wp & 0xffffu)), ax);
          ay = fmaf(hv[i].y, b2f((unsigned short)(wp >> 16)), ay);
        }
      }
      {  // final run touches tile boundary -> atomic
        float* ap = agg + (long)dcur * 128 + (lane << 1);
        atomicAdd(ap, ax); atomicAdd(ap + 1, ay);
      }
      __builtin_amdgcn_wave_barrier();  // scr reused next tile
    }
  } else {
    // ---------- mode 0 fallback: natural order, per-edge atomics ----------
    for (int tile = gw; tile < NTW; tile += nwaves) {
      const int e0 = tile * 16;
      const int er = e0 + n16;
      const float* rp = attr + (long)er * NG;

      float2 p0 = *(const float2*)(rp + q * 8);
      float2 p1 = *(const float2*)(rp + q * 8 + 2);
      float2 p2 = *(const float2*)(rp + q * 8 + 4);
      float2 p3 = *(const float2*)(rp + q * 8 + 6);
      float2 p4 = {0.f, 0.f}, p5 = {0.f, 0.f}, p6 = {0.f, 0.f}, p7 = {0.f, 0.f};
      if (q < 2) {
        const float* rp2 = rp + 32 + q * 8;
        p4 = *(const float2*)(rp2);
        p5 = *(const float2*)(rp2 + 2);
        p6 = *(const float2*)(rp2 + 4);
        p7 = *(const float2*)(rp2 + 6);
      } else if (q == 2) {
        p4 = *(const float2*)(rp + 48);
      }
      union { ushortx8 u; bf16x8 b; } ua, ub;
      ua.u[0] = f2b(p0.x); ua.u[1] = f2b(p0.y); ua.u[2] = f2b(p1.x); ua.u[3] = f2b(p1.y);
      ua.u[4] = f2b(p2.x); ua.u[5] = f2b(p2.y); ua.u[6] = f2b(p3.x); ua.u[7] = f2b(p3.y);
      ub.u[0] = f2b(p4.x); ub.u[1] = f2b(p4.y); ub.u[2] = f2b(p5.x); ub.u[3] = f2b(p5.y);
      ub.u[4] = f2b(p6.x); ub.u[5] = f2b(p6.y); ub.u[6] = f2b(p7.x); ub.u[7] = f2b(p7.y);

#pragma unroll
      for (int t = 0; t < 8; ++t) {
        f32x4 acc = {0.f, 0.f, 0.f, 0.f};
        acc = __builtin_amdgcn_mfma_f32_16x16x32_bf16(ua.b, w1A[t], acc, 0, 0, 0);
        acc = __builtin_amdgcn_mfma_f32_16x16x32_bf16(ub.b, w1B[t], acc, 0, 0, 0);
        int f = t * 16 + n16;
#pragma unroll
        for (int r = 0; r < 4; ++r) {
          int row = q * 4 + r;
          scr[row * 136 + f] = f2b(sspf(acc[r] + b1v[t]));
        }
      }
      __builtin_amdgcn_wave_barrier();

      bf16x8 a2f[4];
#pragma unroll
      for (int ks = 0; ks < 4; ++ks)
        a2f[ks] = *(const bf16x8*)&scr[n16 * 136 + ks * 32 + q * 8];
      __builtin_amdgcn_wave_barrier();

      float cvv[4];
      int srcv[4], dstv[4];
#pragma unroll
      for (int r = 0; r < 4; ++r) {
        cvv[r] = 0.5f * (__builtin_amdgcn_cosf(ew[e0 + q * 4 + r] * 0.05f) + 1.f);
        srcv[r] = ei[e0 + q * 4 + r];
        dstv[r] = ei[E_NUM + e0 + q * 4 + r];
      }

#pragma unroll
      for (int t = 0; t < 8; ++t) {
        int f = t * 16 + n16;
        f32x4 acc = {0.f, 0.f, 0.f, 0.f};
#pragma unroll
        for (int ks = 0; ks < 4; ++ks) {
          bf16x8 bb = *(const bf16x8*)&s_w2[(f << 7) + (((ks * 4 + q) ^ (f & 15)) << 3)];
          acc = __builtin_amdgcn_mfma_f32_16x16x32_bf16(a2f[ks], bb, acc, 0, 0, 0);
        }
#pragma unroll
        for (int r = 0; r < 4; ++r) {
          float msg = h[(long)srcv[r] * 128 + f] * (acc[r] + b2v[t]) * cvv[r];
          atomicAdd(&agg[(long)dstv[r] * 128 + f], msg);
        }
      }
      __builtin_amdgcn_wave_barrier();
    }
  }
}

extern "C" void kernel_launch(void* const* d_in, const int* in_sizes, int n_in,
                              void* d_out, int out_size, void* d_ws, size_t ws_size,
                              hipStream_t stream) {
  const float* x     = (const float*)d_in[0];
  const int*   ei    = (const int*)  d_in[1];
  const float* ew    = (const float*)d_in[2];
  const float* attr  = (const float*)d_in[3];
  const float* w1    = (const float*)d_in[4];
  const float* b1    = (const float*)d_in[5];
  const float* w2    = (const float*)d_in[6];
  const float* b2    = (const float*)d_in[7];
  const float* lin1w = (const float*)d_in[8];
  const float* lin2w = (const float*)d_in[9];
  const float* lin2b = (const float*)d_in[10];
  const float* linw  = (const float*)d_in[11];
  const float* linb  = (const float*)d_in[12];
  float* out = (float*)d_out;

  // workspace layout
  char* base = (char*)d_ws;
  float* agg    = (float*)base;                               // NN*128 f32
  float* h      = agg + (size_t)NN * 128;                     // NN*128 f32
  int*   counts = (int*)(h + (size_t)NN * 128);               // NN
  int*   cursor = counts + NN;                                // NN
  int*   srcS   = cursor + NN;                                // E
  int*   dstS   = srcS + E_NUM;                               // E
  float* cS     = (float*)(dstS + E_NUM);                     // E
  size_t head   = (size_t)((char*)(cS + E_NUM) - base);
  size_t aoff   = (head + 255) & ~(size_t)255;                // 256-B align
  unsigned short* attrS = (unsigned short*)(base + aoff);     // E*64 bf16 (padded rows)
  size_t need   = aoff + (size_t)E_NUM * 64 * sizeof(unsigned short);
  const int mode = (ws_size >= need) ? 1 : 0;

  const int gemm_grid = (NN + 127) / 128;
  (void)hipMemsetAsync(agg, 0, (size_t)NN * 128 * sizeof(float), stream);
  if (mode == 1) {
    (void)hipMemsetAsync(counts, 0, (size_t)NN * sizeof(int), stream);
    k_hist<<<(E_NUM + 255) / 256, 256, 0, stream>>>(ei, counts);
    k_scan<<<1, 1024, 0, stream>>>(counts, cursor);
    k_scatter2<<<(E_NUM + 255) / 256, 256, 0, stream>>>(ei, ew, attr, cursor,
                                                        srcS, dstS, cS, attrS);
  }
  k_mfma_gemm<<<gemm_grid, 256, 0, stream>>>(x, lin1w, nullptr, h, 0, NN);
  k_edge_agg<<<EDGE_BLOCKS, 512, 0, stream>>>(attr, ei, ew, w1, b1, w2, b2, h,
                                              srcS, dstS, cS, attrS, agg, mode);
  k_gemm23<<<gemm_grid, 256, 0, stream>>>(agg, lin2w, lin2b, linw, linb, out, NN);
}